// Round 4
// baseline (219.622 us; speedup 1.0000x reference)
//
#include <hip/hip_runtime.h>

// Problem constants (fixed by setup_inputs)
static constexpr int B    = 16;
static constexpr int L    = 8192;
static constexpr int C    = 256;
static constexpr int C4   = C / 4;          // 64 float4 per row
static constexpr int LOUT = L / 2;          // 4096 output rows per batch
static constexpr int JPT  = 8;              // output rows per thread (per wave)
static constexpr int QPB  = LOUT / JPT;     // 512 chunks per batch
static constexpr int NROW = 2 * JPT + 3;    // 19 input rows per thread

typedef float vfloat4 __attribute__((ext_vector_type(4)));  // native vec for nt-store

__device__ __forceinline__ float4 f4max(float4 a, float4 b) {
    return make_float4(fmaxf(a.x, b.x), fmaxf(a.y, b.y),
                       fmaxf(a.z, b.z), fmaxf(a.w, b.w));
}

// z[j] = w0*m[2j-1] + w1*m[2j] + w2*m[2j+1] + w3*m[2j+2]
//   m[l] = max(x[l], x[l+1]) for l < L-1; m[L-1] = x[L-1]; m[-1] = m[L] = 0
// One thread: 19 clamped row loads -> 18 running maxes -> 8 outputs.
// Halo between neighboring waves is 3 rows per 16 produced (L1/L2-absorbed);
// XCD swizzle keeps neighboring chunks on the same XCD's L2.
__global__ __launch_bounds__(256) void maxblurpool_kernel(
    const float4* __restrict__ x,
    const float*  __restrict__ blur,
    const float*  __restrict__ avg,
    float4*       __restrict__ out)
{
    // HW dispatch is round-robin over 8 XCDs: hw%8 = XCD. Remap so each XCD
    // owns a contiguous chunk range (halo rows stay in that XCD's L2).
    const int nblk    = gridDim.x;                       // 2048
    const int hw      = blockIdx.x;
    const int logical = (hw & 7) * (nblk >> 3) + (hw >> 3);

    const int lane = threadIdx.x & 63;                   // float4 column
    const int wib  = threadIdx.x >> 6;                   // wave in block
    const int q    = logical * 4 + wib;                  // chunk id, [0, 8192)
    const int b    = q >> 9;                             // q / QPB
    const int j0   = (q & (QPB - 1)) * JPT;              // first output row
    const int i0   = 2 * j0 - 1;                         // first input row

    // Coefficients (uniform)
    const float b0 = blur[0], b1 = blur[1], b2 = blur[2];
    const float a0 = avg[0],  a1 = avg[1];
    const float w0 = a0 * b0;
    const float w1 = a0 * b1 + a1 * b0;
    const float w2 = a0 * b2 + a1 * b1;
    const float w3 = a1 * b2;

    const float4* xp = x   + (long)b * L    * C4 + lane;
    float4*       op = out + (long)b * LOUT * C4 + lane;

    // 19 independent loads, rows clamped to [0, L-1]
    float4 xr[NROW];
    #pragma unroll
    for (int k = 0; k < NROW; ++k) {
        int r = i0 + k;
        r = r < 0 ? 0 : (r > L - 1 ? L - 1 : r);
        xr[k] = xp[(long)r * C4];
    }

    // local m[k] == global m[2*j0-1+k]; clamping makes m[L-1]=x[L-1] correct
    float4 m[NROW - 1];
    #pragma unroll
    for (int k = 0; k < NROW - 1; ++k) m[k] = f4max(xr[k], xr[k + 1]);

    #pragma unroll
    for (int t = 0; t < JPT; ++t) {
        // m[-1] = 0 (first output of batch); m[L] = 0 (last output of batch)
        const float W0 = (t == 0        && j0 == 0)           ? 0.f : w0;
        const float W3 = (t == JPT - 1  && j0 == LOUT - JPT)  ? 0.f : w3;
        const float4 ma = m[2 * t], mb = m[2 * t + 1];
        const float4 mc = m[2 * t + 2], md = m[2 * t + 3];
        vfloat4 z;
        z.x = W0 * ma.x + w1 * mb.x + w2 * mc.x + W3 * md.x;
        z.y = W0 * ma.y + w1 * mb.y + w2 * mc.y + W3 * md.y;
        z.z = W0 * ma.z + w1 * mb.z + w2 * mc.z + W3 * md.z;
        z.w = W0 * ma.w + w1 * mb.w + w2 * mc.w + W3 * md.w;
        // Output is never re-read: nontemporal keeps L2 free for input halo
        __builtin_nontemporal_store(z, (vfloat4*)&op[(long)(j0 + t) * C4]);
    }
}

extern "C" void kernel_launch(void* const* d_in, const int* in_sizes, int n_in,
                              void* d_out, int out_size, void* d_ws, size_t ws_size,
                              hipStream_t stream) {
    const float4* x    = (const float4*)d_in[0];
    const float*  blur = (const float*)d_in[1];
    const float*  avg  = (const float*)d_in[2];
    float4*       out  = (float4*)d_out;

    const int total_threads = B * QPB * C4;     // 524288
    const int block = 256;
    const int grid  = total_threads / block;    // 2048 blocks
    maxblurpool_kernel<<<grid, block, 0, stream>>>(x, blur, avg, out);
}

// Round 5
// 211.857 us; speedup vs baseline: 1.0367x; 1.0367x over previous
//
#include <hip/hip_runtime.h>

// Problem constants (fixed by setup_inputs)
static constexpr int B     = 16;
static constexpr int L     = 8192;
static constexpr int C     = 256;
static constexpr int C4    = C / 4;        // 64 float4 per row
static constexpr int LOUT  = L / 2;        // 4096 output rows per batch
static constexpr int PAIRS = LOUT / 2;     // 2048 output-row pairs per batch

__device__ __forceinline__ float4 f4max(float4 a, float4 b) {
    return make_float4(fmaxf(a.x, b.x), fmaxf(a.y, b.y),
                       fmaxf(a.z, b.z), fmaxf(a.w, b.w));
}

// z[j] = w0*m[2j-1] + w1*m[2j] + w2*m[2j+1] + w3*m[2j+2]
//   m[l] = max(x[l], x[l+1]) for l < L-1; m[L-1] = x[L-1]; m[-1] = m[L] = 0
// One thread -> outputs {j, j+1} (j even) for one float4 column: 7 independent
// clamped loads, branch-free, ~56 VGPRs -> full occupancy (R2 structure).
// XCD swizzle: consecutive logical blocks share 3 halo rows; mapping them to
// the same XCD keeps the halo in that XCD's L2 (round-robin would split it).
__global__ __launch_bounds__(256) void maxblurpool_kernel(
    const float4* __restrict__ x,
    const float*  __restrict__ blur,
    const float*  __restrict__ avg,
    float4*       __restrict__ out)
{
    // HW round-robin: XCD = blockIdx % 8. Remap so each XCD owns a
    // contiguous range of logical blocks.
    const int nblk    = gridDim.x;                   // 8192
    const int hw      = blockIdx.x;
    const int logical = (hw & 7) * (nblk >> 3) + (hw >> 3);

    const int t  = logical * 256 + threadIdx.x;
    const int c4 = t & (C4 - 1);           // lane -> float4 column (coalesced)
    const int p  = t >> 6;                 // wave-uniform pair index
    const int b  = p >> 11;                // p / PAIRS   (PAIRS == 2048)
    const int pj = p & (PAIRS - 1);
    const int j  = pj << 1;                // first output row (even)
    const int i  = j << 1;                 // center input row; i+3 <= L-1 always

    // Coefficients (uniform)
    const float b0 = blur[0], b1 = blur[1], b2 = blur[2];
    const float a0 = avg[0],  a1 = avg[1];
    const float w0 = a0 * b0;
    const float w1 = a0 * b1 + a1 * b0;
    const float w2 = a0 * b2 + a1 * b1;
    const float w3 = a1 * b2;
    const float w0a = (j == 0)            ? 0.f : w0;  // m[-1] = 0
    const float w3b = (j + 1 == LOUT - 1) ? 0.f : w3;  // m[L] = 0

    const float4* xp = x   + (long)b * L    * C4 + c4;
    float4*       op = out + (long)b * LOUT * C4 + c4;

    // Clamped row indices (only first/last pair actually clamp)
    const int rm1 = (i > 0)          ? i - 1 : 0;
    const int r4  = (i + 4 <= L - 1) ? i + 4 : L - 1;
    const int r5  = (i + 5 <= L - 1) ? i + 5 : L - 1;

    // 7 independent loads — all issued before any use
    const float4 xm1 = xp[(long)rm1     * C4];
    const float4 x0  = xp[(long)i       * C4];
    const float4 x1  = xp[(long)(i + 1) * C4];
    const float4 x2  = xp[(long)(i + 2) * C4];
    const float4 x3  = xp[(long)(i + 3) * C4];
    const float4 x4  = xp[(long)r4      * C4];
    const float4 x5  = xp[(long)r5      * C4];

    const float4 m0 = f4max(xm1, x0);  // m[2j-1] (w0a kills it at j==0)
    const float4 m1 = f4max(x0,  x1);  // m[2j]
    const float4 m2 = f4max(x1,  x2);  // m[2j+1] == m[2(j+1)-1]
    const float4 m3 = f4max(x2,  x3);  // m[2j+2] == m[2(j+1)]
    const float4 m4 = f4max(x3,  x4);  // m[2j+3]; clamp gives m[L-1]=x[L-1] at the end
    const float4 m5 = f4max(x4,  x5);  // m[2j+4] (w3b kills it at j+1==LOUT-1)

    float4 za, zb;
    za.x = w0a * m0.x + w1 * m1.x + w2 * m2.x + w3  * m3.x;
    za.y = w0a * m0.y + w1 * m1.y + w2 * m2.y + w3  * m3.y;
    za.z = w0a * m0.z + w1 * m1.z + w2 * m2.z + w3  * m3.z;
    za.w = w0a * m0.w + w1 * m1.w + w2 * m2.w + w3  * m3.w;
    zb.x = w0  * m2.x + w1 * m3.x + w2 * m4.x + w3b * m5.x;
    zb.y = w0  * m2.y + w1 * m3.y + w2 * m4.y + w3b * m5.y;
    zb.z = w0  * m2.z + w1 * m3.z + w2 * m4.z + w3b * m5.z;
    zb.w = w0  * m2.w + w1 * m3.w + w2 * m4.w + w3b * m5.w;

    op[(long)j       * C4] = za;
    op[(long)(j + 1) * C4] = zb;
}

extern "C" void kernel_launch(void* const* d_in, const int* in_sizes, int n_in,
                              void* d_out, int out_size, void* d_ws, size_t ws_size,
                              hipStream_t stream) {
    const float4* x    = (const float4*)d_in[0];
    const float*  blur = (const float*)d_in[1];
    const float*  avg  = (const float*)d_in[2];
    float4*       out  = (float4*)d_out;

    const int total_threads = B * PAIRS * C4;   // 2,097,152
    const int block = 256;
    const int grid  = total_threads / block;    // 8192 blocks
    maxblurpool_kernel<<<grid, block, 0, stream>>>(x, blur, avg, out);
}